// Round 11
// baseline (205.374 us; speedup 1.0000x reference)
//
#include <hip/hip_runtime.h>
#include <cstdint>
#include <cstddef>

typedef __attribute__((ext_vector_type(8))) __bf16 bf16x8;
typedef __attribute__((ext_vector_type(4))) float f32x4;
typedef __attribute__((ext_vector_type(2))) float f32x2;
typedef __attribute__((ext_vector_type(2))) unsigned short u16x2;
typedef __attribute__((ext_vector_type(4))) unsigned short u16x4;
typedef __attribute__((ext_vector_type(8))) unsigned short u16x8;

static constexpr int Bz = 2, Sz = 2048, Gz = 4, Cz = 2048;
static constexpr int Hh = 16, EDz = 1024;
static constexpr int Tz = Bz * Sz;          // 4096 tokens
static constexpr int NALL = Gz * Cz + Cz;   // 10240 GEMM output cols

__constant__ int OFF16[16] = {0, 100003, 200022, 300065, 400114, 500171, 600240,
                              700343, 800452, 900581, 1000732, 1100885, 1201054,
                              1301237, 1401426, 1501619};

__device__ __forceinline__ float bf2f(unsigned short s) {
  union { unsigned u; float f; } x; x.u = ((unsigned)s) << 16; return x.f;
}
__device__ __forceinline__ unsigned short f2bf(float f) {
  union { float f; unsigned u; } x; x.f = f;
  unsigned r = x.u + 0x7fff + ((x.u >> 16) & 1);
  return (unsigned short)(r >> 16);
}

// ---------------- merged prep: weight transpose + gather + zero sums ----------
// blocks [0,10240): prepw | [10240,14336): gather | [14336,14544): zero sums
__global__ __launch_bounds__(256) void k_prep(const float* __restrict__ key_w,
                                              const float* __restrict__ value_w,
                                              const float* __restrict__ table,
                                              const int* __restrict__ ids,
                                              unsigned short* __restrict__ Wt,
                                              unsigned short* __restrict__ emb,
                                              float* __restrict__ sums) {
  const int b = blockIdx.x;
  __shared__ float tile[32][33];
  if (b < 10240) {
    const int mat = b / 2048;
    const int inner = b - mat * 2048;
    const int ot = inner & 63, kt = inner >> 6;
    const float* src = (mat < 4) ? (key_w + (size_t)mat * EDz * Cz) : value_w;
    const int tx = threadIdx.x & 31, ty = threadIdx.x >> 5;
#pragma unroll
    for (int i = 0; i < 4; i++)
      tile[ty + i * 8][tx] = src[(size_t)(kt * 32 + ty + i * 8) * Cz + ot * 32 + tx];
    __syncthreads();
    // vectorized store: thread = (nl, kq); writes u16x4 at k = kq*4
    const int nl = threadIdx.x >> 3, kq = threadIdx.x & 7;
    u16x4 o;
#pragma unroll
    for (int c = 0; c < 4; c++) o[c] = f2bf(tile[kq * 4 + c][nl]);
    *reinterpret_cast<u16x4*>(
        &Wt[(size_t)(mat * Cz + ot * 32 + nl) * EDz + kt * 32 + kq * 4]) = o;
  } else if (b < 14336) {
    const int t = b - 10240;
    const int tid = threadIdx.x;
    const int h = tid >> 4;
    const int d = (tid & 15) * 4;
    const long row = (long)(ids[t * Hh + h] + OFF16[h]);
    f32x4 v = *reinterpret_cast<const f32x4*>(table + row * 64 + d);
    u16x4 o;
#pragma unroll
    for (int i = 0; i < 4; i++) o[i] = f2bf(v[i]);
    *reinterpret_cast<u16x4*>(emb + (size_t)t * EDz + tid * 4) = o;
  } else {
    const int i = (b - 14336) * 256 + threadIdx.x;
    if (i < 53248) sums[i] = 0.f;   // q2[16384], k2[16384], qwk[16384], v2[4096]
  }
}

// ---------------- fused GEMM (r5-proven: 256x256, BK=64, 8-phase) ----------
#define GEMM_BAR  asm volatile("s_barrier" ::: "memory")
#define GEMM_V4   asm volatile("s_waitcnt vmcnt(4)" ::: "memory")

__global__ __launch_bounds__(512, 2) void k_gemm8f(const unsigned short* __restrict__ A,
                                                   const unsigned short* __restrict__ Bw,
                                                   const float* __restrict__ hidden,
                                                   const float* __restrict__ key_b,
                                                   const float* __restrict__ value_b,
                                                   const float* __restrict__ q_scale,
                                                   const float* __restrict__ k_scale,
                                                   float* __restrict__ sums,
                                                   unsigned short* __restrict__ vbuf) {
  __shared__ unsigned short s_lds[65536];  // 128 KiB
  char* lds_c = (char*)s_lds;

  const int tid = threadIdx.x;
  const int wid = tid >> 6, lane = tid & 63;
  const int wr = wid >> 2, wc = wid & 3;

  const int bid = blockIdx.x;
  const int swz = (bid & 7) * 80 + (bid >> 3);
  const int bm = swz / 40, bn = swz % 40;
  const int m0 = bm * 256, n0 = bn * 256;

  int rq[2], kq[2];
#pragma unroll
  for (int q = 0; q < 2; q++) {
    int x = q * 8192 + wid * 1024 + lane * 16;
    int y = x ^ (((x >> 9) & 1) << 5);
    rq[q] = ((y >> 11) & 7) * 16 + ((y >> 6) & 15);
    kq[q] = ((y >> 10) & 1) * 32 + ((y >> 1) & 31);
  }
  const int rdb = (((lane & 15) << 6) + ((lane >> 4) << 4)) ^ (((lane >> 3) & 1) << 5);

  const unsigned short* Arow0 = A + (size_t)m0 * EDz;
  const unsigned short* Arow1 = A + (size_t)(m0 + 128) * EDz;
  const unsigned short* Brow0 = Bw + (size_t)n0 * EDz;
  const unsigned short* Brow1 = Bw + (size_t)(n0 + 128) * EDz;

  auto STAGE = [&](const unsigned short* grow, int ldsOff, int kt) {
#pragma unroll
    for (int q = 0; q < 2; q++) {
      const unsigned short* src = grow + (size_t)rq[q] * EDz + kt * 64 + kq[q];
      __builtin_amdgcn_global_load_lds(
          (const __attribute__((address_space(1))) void*)src,
          (__attribute__((address_space(3))) void*)(lds_c + ldsOff + q * 8192 + wid * 1024),
          16, 0, 0);
    }
  };

  f32x4 acc[8][4] = {};
  bf16x8 Af[4][2], Bl[2][2], Bh[2][2];

  auto RD_A = [&](int buf, int msel) {
    const char* p = lds_c + buf * 32768 + wr * 16384 + rdb;
#pragma unroll
    for (int m = 0; m < 4; m++)
#pragma unroll
      for (int ks = 0; ks < 2; ks++)
        Af[m][ks] = *reinterpret_cast<const bf16x8*>(p + (msel * 4 + m) * 2048 + ks * 1024);
  };
  auto RD_B = [&](int buf, int nsel, bf16x8 (&Bf)[2][2]) {
    const char* p = lds_c + 65536 + buf * 32768 + (wc >> 1) * 16384 + (wc & 1) * 8192 + rdb;
#pragma unroll
    for (int n = 0; n < 2; n++)
#pragma unroll
      for (int ks = 0; ks < 2; ks++)
        Bf[n][ks] = *reinterpret_cast<const bf16x8*>(p + (nsel * 2 + n) * 2048 + ks * 1024);
  };
  auto MM = [&](int msel, int nsel, bf16x8 (&Bf)[2][2]) {
    __builtin_amdgcn_s_setprio(1);
#pragma unroll
    for (int m = 0; m < 4; m++)
#pragma unroll
      for (int n = 0; n < 2; n++)
#pragma unroll
        for (int ks = 0; ks < 2; ks++)
          acc[msel * 4 + m][nsel * 2 + n] = __builtin_amdgcn_mfma_f32_16x16x32_bf16(
              Af[m][ks], Bf[n][ks], acc[msel * 4 + m][nsel * 2 + n], 0, 0, 0);
    __builtin_amdgcn_s_setprio(0);
  };

  STAGE(Arow0, 0,             0);
  STAGE(Arow1, 16384,         0);
  STAGE(Brow0, 65536,         0);
  STAGE(Brow1, 65536 + 16384, 0);
  STAGE(Brow0, 65536 + 32768,         1);
  STAGE(Brow1, 65536 + 32768 + 16384, 1);
  GEMM_V4;
  GEMM_BAR;

  for (int i = 0; i < 8; ++i) {
    const int o  = 2 * i + 1;
    const int t2 = (2 * i + 2 > 15) ? 15 : 2 * i + 2;
    const int t3 = (2 * i + 3 > 15) ? 15 : 2 * i + 3;
    RD_A(0, 0); RD_B(0, 0, Bl);
    STAGE(Arow0, 32768, o);
    GEMM_BAR; MM(0, 0, Bl); GEMM_BAR;
    RD_B(0, 1, Bh);
    STAGE(Arow1, 32768 + 16384, o);
    GEMM_BAR; MM(0, 1, Bh); GEMM_BAR;
    RD_A(0, 1);
    STAGE(Brow0, 65536, t2);
    GEMM_BAR; MM(1, 0, Bl); GEMM_BAR;
    STAGE(Brow1, 65536 + 16384, t2);
    GEMM_V4;
    GEMM_BAR; MM(1, 1, Bh); GEMM_BAR;
    RD_A(1, 0); RD_B(1, 0, Bl);
    STAGE(Arow0, 0, t2);
    GEMM_BAR; MM(0, 0, Bl); GEMM_BAR;
    RD_B(1, 1, Bh);
    STAGE(Arow1, 16384, t2);
    GEMM_BAR; MM(0, 1, Bh); GEMM_BAR;
    RD_A(1, 1);
    STAGE(Brow0, 65536 + 32768, t3);
    GEMM_BAR; MM(1, 0, Bl); GEMM_BAR;
    STAGE(Brow1, 65536 + 32768 + 16384, t3);
    GEMM_V4;
    GEMM_BAR; MM(1, 1, Bh); GEMM_BAR;
  }

  float* sum_q2  = sums;
  float* sum_k2  = sums + 16384;
  float* sum_qwk = sums + 32768;
  float* sum_v2  = sums + 49152;

  if (n0 < 8192) {
    // ---- key epilogue: k -> swizzled LDS, then coalesced reduction pass ----
    const int g = n0 >> 11;
#pragma unroll
    for (int mrep = 0; mrep < 8; mrep++) {
      const int rowb = wr * 128 + mrep * 16 + (lane >> 4) * 4;
#pragma unroll
      for (int nrep = 0; nrep < 4; nrep++) {
        const int coll = wc * 64 + nrep * 16 + (lane & 15);
        const float kb = key_b[n0 + coll];
#pragma unroll
        for (int t = 0; t < 4; t++) {
          const int row = rowb + t;
          const int addr = (row * 512 + coll * 2) ^ ((row & 15) << 4);
          *reinterpret_cast<unsigned short*>(lds_c + addr) =
              f2bf(acc[mrep][nrep][t] + kb);
        }
      }
    }
    __syncthreads();
    const int wrow = wid * 32;
    const int lrow = lane >> 3;
    const int lsub = lane & 7;
#pragma unroll
    for (int rr = 0; rr < 4; rr++) {
      const int row = wrow + rr * 8 + lrow;
      const int grow = m0 + row;
      const float* hp = hidden + (size_t)grow * 8192 + n0;
      float a_k2 = 0.f, a_qwk = 0.f, a_q2 = 0.f;
#pragma unroll
      for (int c8 = 0; c8 < 4; c8++) {
        const int lc = c8 * 64 + lsub * 8;
        const int addr = (row * 512 + lc * 2) ^ ((row & 15) << 4);
        bf16x8 k8 = *reinterpret_cast<const bf16x8*>(lds_c + addr);
        f32x4 h0 = *reinterpret_cast<const f32x4*>(hp + lc);
        f32x4 h1 = *reinterpret_cast<const f32x4*>(hp + lc + 4);
        f32x4 qs0 = *reinterpret_cast<const f32x4*>(q_scale + n0 + lc);
        f32x4 qs1 = *reinterpret_cast<const f32x4*>(q_scale + n0 + lc + 4);
        f32x4 ks0 = *reinterpret_cast<const f32x4*>(k_scale + n0 + lc);
        f32x4 ks1 = *reinterpret_cast<const f32x4*>(k_scale + n0 + lc + 4);
#pragma unroll
        for (int i = 0; i < 8; i++) {
          const float kf = (float)k8[i];
          const float hf = (i < 4) ? h0[i] : h1[i - 4];
          const float wf = ((i < 4) ? qs0[i] : qs1[i - 4]) *
                           ((i < 4) ? ks0[i] : ks1[i - 4]);
          a_k2  += kf * kf;
          a_qwk += kf * hf * wf;
          a_q2  += hf * hf;
        }
      }
#pragma unroll
      for (int msk = 1; msk <= 4; msk <<= 1) {
        a_k2  += __shfl_xor(a_k2, msk);
        a_qwk += __shfl_xor(a_qwk, msk);
        a_q2  += __shfl_xor(a_q2, msk);
      }
      if (lsub == 0) {
        const int idx = grow * 4 + g;
        atomicAdd(&sum_k2[idx], a_k2);
        atomicAdd(&sum_qwk[idx], a_qwk);
        atomicAdd(&sum_q2[idx], a_q2);
      }
    }
  } else {
    // ---- value epilogue: store bf16 + sum v^2 per row ----
#pragma unroll
    for (int mrep = 0; mrep < 8; mrep++) {
      const int rowb = m0 + wr * 128 + mrep * 16 + (lane >> 4) * 4;
      float av2[4] = {0.f, 0.f, 0.f, 0.f};
#pragma unroll
      for (int nrep = 0; nrep < 4; nrep++) {
        const int vcol = n0 - 8192 + wc * 64 + nrep * 16 + (lane & 15);
        const float vb = value_b[vcol];
#pragma unroll
        for (int t = 0; t < 4; t++) {
          const float v = acc[mrep][nrep][t] + vb;
          av2[t] += v * v;
          vbuf[(size_t)(rowb + t) * 2048 + vcol] = f2bf(v);
        }
      }
#pragma unroll
      for (int t = 0; t < 4; t++) {
        float a = av2[t];
#pragma unroll
        for (int msk = 1; msk <= 8; msk <<= 1) a += __shfl_xor(a, msk);
        if ((lane & 15) == 0) atomicAdd(&sum_v2[rowb + t], a);
      }
    }
  }
}

// ---------------- conv: all 4 g per block; vbuf read ONCE per token ----------
// 1024 threads, 2 channels/thread; gate/rstd computed in-block into LDS.
__global__ __launch_bounds__(1024, 4) void k_conv(const unsigned short* __restrict__ vbuf,
                                                  const float* __restrict__ sums,
                                                  const float* __restrict__ conv_scale,
                                                  const float* __restrict__ conv_w,
                                                  float* __restrict__ out) {
  const int th = threadIdx.x;                 // 0..1023
  const int r = blockIdx.x % 3, seg = blockIdx.x / 3;   // 3 residues x 32 segs
  const int b = blockIdx.y;
  const int c2 = th * 2;                      // 0..2046
  const int s_begin = seg * 64, s_end = s_begin + 64;

  __shared__ float g_lds[4][73], r_lds[4][73];
  if (th < 292) {
    const int g = th / 73, j = th % 73;
    const int s = s_begin - 9 + j;
    if (s >= 0) {
      const int t = b * Sz + s;
      const int idx = t * 4 + g;
      const float invC = 1.f / 2048.f;
      const float inv_sqrtC = 0.02209708691f;
      float rqv = rsqrtf(sums[idx] * invC + 1e-6f);
      float rkv = rsqrtf(sums[16384 + idx] * invC + 1e-6f);
      float qk = sums[32768 + idx] * rqv * rkv * inv_sqrtC;
      float l = sqrtf(fmaxf(fabsf(qk), 1e-6f));
      l = (qk < 0.f) ? -l : l;
      float gate = 1.f / (1.f + expf(-l));
      g_lds[g][j] = gate;
      r_lds[g][j] = rsqrtf(gate * gate * (sums[49152 + t] * invC) + 1e-5f);
    } else {
      g_lds[g][j] = 0.f; r_lds[g][j] = 0.f;
    }
  }
  __syncthreads();

  float cs[4][2], w0[4][2], w1[4][2], w2[4][2], w3[4][2];
#pragma unroll
  for (int g = 0; g < 4; g++) {
    const int ch = g * Cz + c2;
    f32x2 a  = *reinterpret_cast<const f32x2*>(conv_scale + ch);
    f32x2 t0 = *reinterpret_cast<const f32x2*>(conv_w + 0 * 8192 + ch);
    f32x2 t1 = *reinterpret_cast<const f32x2*>(conv_w + 1 * 8192 + ch);
    f32x2 t2 = *reinterpret_cast<const f32x2*>(conv_w + 2 * 8192 + ch);
    f32x2 t3 = *reinterpret_cast<const f32x2*>(conv_w + 3 * 8192 + ch);
#pragma unroll
    for (int i = 0; i < 2; i++) {
      cs[g][i] = a[i];
      w0[g][i] = t0[i]; w1[g][i] = t1[i];
      w2[g][i] = t2[i]; w3[g][i] = t3[i];
    }
  }

  const int s0 = s_begin + ((r - s_begin) % 3 + 3) % 3;

  float p1[4][2], p2[4][2], p3[4][2];
  auto ldxn = [&](int s, float (*dst)[2]) {
    if (s < 0) {
#pragma unroll
      for (int g = 0; g < 4; g++) { dst[g][0] = 0.f; dst[g][1] = 0.f; }
      return;
    }
    const int t = b * Sz + s;
    const int li = s - s_begin + 9;
    u16x2 raw = *reinterpret_cast<const u16x2*>(vbuf + (size_t)t * 2048 + c2);
#pragma unroll
    for (int g = 0; g < 4; g++) {
      const float grs = g_lds[g][li] * r_lds[g][li];
#pragma unroll
      for (int i = 0; i < 2; i++) dst[g][i] = bf2f(raw[i]) * grs * cs[g][i];
    }
  };
  ldxn(s0 - 3, p1); ldxn(s0 - 6, p2); ldxn(s0 - 9, p3);

  for (int s = s0; s < s_end; s += 3) {
    const int t = b * Sz + s;
    const int li = s - s_begin + 9;
    u16x2 raw = *reinterpret_cast<const u16x2*>(vbuf + (size_t)t * 2048 + c2);
    const float v0f = bf2f(raw[0]), v1f = bf2f(raw[1]);
#pragma unroll
    for (int g = 0; g < 4; g++) {
      const float gate = g_lds[g][li];
      const float rsc = r_lds[g][li];
      f32x2 ov;
#pragma unroll
      for (int i = 0; i < 2; i++) {
        const float v = ((i == 0) ? v0f : v1f) * gate;
        const float xn = v * rsc * cs[g][i];
        const float y = w3[g][i] * xn + w2[g][i] * p1[g][i] +
                        w1[g][i] * p2[g][i] + w0[g][i] * p3[g][i];
        const float sy = y / (1.f + expf(-y));
        ov[i] = v + sy;
        p3[g][i] = p2[g][i]; p2[g][i] = p1[g][i]; p1[g][i] = xn;
      }
      *reinterpret_cast<f32x2*>(out + (size_t)t * (Gz * Cz) + g * Cz + c2) = ov;
    }
  }
}

extern "C" void kernel_launch(void* const* d_in, const int* in_sizes, int n_in,
                              void* d_out, int out_size, void* d_ws, size_t ws_size,
                              hipStream_t stream) {
  const float* hidden     = (const float*)d_in[0];
  const int*   hashids    = (const int*)d_in[1];
  const float* table      = (const float*)d_in[2];
  const float* key_w      = (const float*)d_in[3];
  const float* key_b      = (const float*)d_in[4];
  const float* k_scale    = (const float*)d_in[5];
  const float* q_scale    = (const float*)d_in[6];
  const float* value_w    = (const float*)d_in[7];
  const float* value_b    = (const float*)d_in[8];
  const float* conv_scale = (const float*)d_in[9];
  const float* conv_w     = (const float*)d_in[10];
  float* out = (float*)d_out;
  char* ws = (char*)d_ws;

  unsigned short* emb  = (unsigned short*)(ws + 0);          //  8,388,608 B
  unsigned short* Wt   = (unsigned short*)(ws + 8388608);    // 20,971,520 B
  unsigned short* vbuf = (unsigned short*)(ws + 29360128);   // 16,777,216 B
  float* sums  = (float*)(ws + 46137344);                    //    212,992 B

  k_prep<<<dim3(14544), dim3(256), 0, stream>>>(key_w, value_w, table, hashids,
                                                Wt, emb, sums);
  k_gemm8f<<<dim3(640), dim3(512), 0, stream>>>(emb, Wt, hidden, key_b, value_b,
                                                q_scale, k_scale, sums, vbuf);
  k_conv<<<dim3(96, 2), dim3(1024), 0, stream>>>(vbuf, sums, conv_scale, conv_w, out);
}

// Round 12
// 192.167 us; speedup vs baseline: 1.0687x; 1.0687x over previous
//
#include <hip/hip_runtime.h>
#include <cstdint>
#include <cstddef>

typedef __attribute__((ext_vector_type(8))) __bf16 bf16x8;
typedef __attribute__((ext_vector_type(4))) float f32x4;
typedef __attribute__((ext_vector_type(4))) unsigned short u16x4;
typedef __attribute__((ext_vector_type(8))) unsigned short u16x8;

static constexpr int Bz = 2, Sz = 2048, Gz = 4, Cz = 2048;
static constexpr int Hh = 16, EDz = 1024;
static constexpr int Tz = Bz * Sz;          // 4096 tokens
static constexpr int NALL = Gz * Cz + Cz;   // 10240 GEMM output cols

__constant__ int OFF16[16] = {0, 100003, 200022, 300065, 400114, 500171, 600240,
                              700343, 800452, 900581, 1000732, 1100885, 1201054,
                              1301237, 1401426, 1501619};

__device__ __forceinline__ float bf2f(unsigned short s) {
  union { unsigned u; float f; } x; x.u = ((unsigned)s) << 16; return x.f;
}
__device__ __forceinline__ unsigned short f2bf(float f) {
  union { float f; unsigned u; } x; x.f = f;
  unsigned r = x.u + 0x7fff + ((x.u >> 16) & 1);
  return (unsigned short)(r >> 16);
}

// ---------------- merged prep: weight transpose + gather + zero sums ----------
// blocks [0,10240): prepw | [10240,14336): gather | [14336,14544): zero sums
__global__ __launch_bounds__(256) void k_prep(const float* __restrict__ key_w,
                                              const float* __restrict__ value_w,
                                              const float* __restrict__ table,
                                              const int* __restrict__ ids,
                                              unsigned short* __restrict__ Wt,
                                              unsigned short* __restrict__ emb,
                                              float* __restrict__ sums) {
  const int b = blockIdx.x;
  __shared__ float tile[32][33];
  if (b < 10240) {
    const int mat = b / 2048;
    const int inner = b - mat * 2048;
    const int ot = inner & 63, kt = inner >> 6;
    const float* src = (mat < 4) ? (key_w + (size_t)mat * EDz * Cz) : value_w;
    const int tx = threadIdx.x & 31, ty = threadIdx.x >> 5;
#pragma unroll
    for (int i = 0; i < 4; i++)
      tile[ty + i * 8][tx] = src[(size_t)(kt * 32 + ty + i * 8) * Cz + ot * 32 + tx];
    __syncthreads();
    // vectorized store: thread = (nl, kq); writes u16x4 at k = kq*4
    const int nl = threadIdx.x >> 3, kq = threadIdx.x & 7;
    u16x4 o;
#pragma unroll
    for (int c = 0; c < 4; c++) o[c] = f2bf(tile[kq * 4 + c][nl]);
    *reinterpret_cast<u16x4*>(
        &Wt[(size_t)(mat * Cz + ot * 32 + nl) * EDz + kt * 32 + kq * 4]) = o;
  } else if (b < 14336) {
    const int t = b - 10240;
    const int tid = threadIdx.x;
    const int h = tid >> 4;
    const int d = (tid & 15) * 4;
    const long row = (long)(ids[t * Hh + h] + OFF16[h]);
    f32x4 v = *reinterpret_cast<const f32x4*>(table + row * 64 + d);
    u16x4 o;
#pragma unroll
    for (int i = 0; i < 4; i++) o[i] = f2bf(v[i]);
    *reinterpret_cast<u16x4*>(emb + (size_t)t * EDz + tid * 4) = o;
  } else {
    const int i = (b - 14336) * 256 + threadIdx.x;
    if (i < 53248) sums[i] = 0.f;   // q2[16384], k2[16384], qwk[16384], v2[4096]
  }
}

// ---------------- fused GEMM (r5-proven: 256x256, BK=64, 8-phase) ----------
#define GEMM_BAR  asm volatile("s_barrier" ::: "memory")
#define GEMM_V4   asm volatile("s_waitcnt vmcnt(4)" ::: "memory")

__global__ __launch_bounds__(512, 2) void k_gemm8f(const unsigned short* __restrict__ A,
                                                   const unsigned short* __restrict__ Bw,
                                                   const float* __restrict__ hidden,
                                                   const float* __restrict__ key_b,
                                                   const float* __restrict__ value_b,
                                                   const float* __restrict__ q_scale,
                                                   const float* __restrict__ k_scale,
                                                   float* __restrict__ sums,
                                                   unsigned short* __restrict__ vbuf) {
  __shared__ unsigned short s_lds[65536];  // 128 KiB
  char* lds_c = (char*)s_lds;

  const int tid = threadIdx.x;
  const int wid = tid >> 6, lane = tid & 63;
  const int wr = wid >> 2, wc = wid & 3;

  const int bid = blockIdx.x;
  const int swz = (bid & 7) * 80 + (bid >> 3);
  const int bm = swz / 40, bn = swz % 40;
  const int m0 = bm * 256, n0 = bn * 256;

  int rq[2], kq[2];
#pragma unroll
  for (int q = 0; q < 2; q++) {
    int x = q * 8192 + wid * 1024 + lane * 16;
    int y = x ^ (((x >> 9) & 1) << 5);
    rq[q] = ((y >> 11) & 7) * 16 + ((y >> 6) & 15);
    kq[q] = ((y >> 10) & 1) * 32 + ((y >> 1) & 31);
  }
  const int rdb = (((lane & 15) << 6) + ((lane >> 4) << 4)) ^ (((lane >> 3) & 1) << 5);

  const unsigned short* Arow0 = A + (size_t)m0 * EDz;
  const unsigned short* Arow1 = A + (size_t)(m0 + 128) * EDz;
  const unsigned short* Brow0 = Bw + (size_t)n0 * EDz;
  const unsigned short* Brow1 = Bw + (size_t)(n0 + 128) * EDz;

  auto STAGE = [&](const unsigned short* grow, int ldsOff, int kt) {
#pragma unroll
    for (int q = 0; q < 2; q++) {
      const unsigned short* src = grow + (size_t)rq[q] * EDz + kt * 64 + kq[q];
      __builtin_amdgcn_global_load_lds(
          (const __attribute__((address_space(1))) void*)src,
          (__attribute__((address_space(3))) void*)(lds_c + ldsOff + q * 8192 + wid * 1024),
          16, 0, 0);
    }
  };

  f32x4 acc[8][4] = {};
  bf16x8 Af[4][2], Bl[2][2], Bh[2][2];

  auto RD_A = [&](int buf, int msel) {
    const char* p = lds_c + buf * 32768 + wr * 16384 + rdb;
#pragma unroll
    for (int m = 0; m < 4; m++)
#pragma unroll
      for (int ks = 0; ks < 2; ks++)
        Af[m][ks] = *reinterpret_cast<const bf16x8*>(p + (msel * 4 + m) * 2048 + ks * 1024);
  };
  auto RD_B = [&](int buf, int nsel, bf16x8 (&Bf)[2][2]) {
    const char* p = lds_c + 65536 + buf * 32768 + (wc >> 1) * 16384 + (wc & 1) * 8192 + rdb;
#pragma unroll
    for (int n = 0; n < 2; n++)
#pragma unroll
      for (int ks = 0; ks < 2; ks++)
        Bf[n][ks] = *reinterpret_cast<const bf16x8*>(p + (nsel * 2 + n) * 2048 + ks * 1024);
  };
  auto MM = [&](int msel, int nsel, bf16x8 (&Bf)[2][2]) {
    __builtin_amdgcn_s_setprio(1);
#pragma unroll
    for (int m = 0; m < 4; m++)
#pragma unroll
      for (int n = 0; n < 2; n++)
#pragma unroll
        for (int ks = 0; ks < 2; ks++)
          acc[msel * 4 + m][nsel * 2 + n] = __builtin_amdgcn_mfma_f32_16x16x32_bf16(
              Af[m][ks], Bf[n][ks], acc[msel * 4 + m][nsel * 2 + n], 0, 0, 0);
    __builtin_amdgcn_s_setprio(0);
  };

  STAGE(Arow0, 0,             0);
  STAGE(Arow1, 16384,         0);
  STAGE(Brow0, 65536,         0);
  STAGE(Brow1, 65536 + 16384, 0);
  STAGE(Brow0, 65536 + 32768,         1);
  STAGE(Brow1, 65536 + 32768 + 16384, 1);
  GEMM_V4;
  GEMM_BAR;

  for (int i = 0; i < 8; ++i) {
    const int o  = 2 * i + 1;
    const int t2 = (2 * i + 2 > 15) ? 15 : 2 * i + 2;
    const int t3 = (2 * i + 3 > 15) ? 15 : 2 * i + 3;
    RD_A(0, 0); RD_B(0, 0, Bl);
    STAGE(Arow0, 32768, o);
    GEMM_BAR; MM(0, 0, Bl); GEMM_BAR;
    RD_B(0, 1, Bh);
    STAGE(Arow1, 32768 + 16384, o);
    GEMM_BAR; MM(0, 1, Bh); GEMM_BAR;
    RD_A(0, 1);
    STAGE(Brow0, 65536, t2);
    GEMM_BAR; MM(1, 0, Bl); GEMM_BAR;
    STAGE(Brow1, 65536 + 16384, t2);
    GEMM_V4;
    GEMM_BAR; MM(1, 1, Bh); GEMM_BAR;
    RD_A(1, 0); RD_B(1, 0, Bl);
    STAGE(Arow0, 0, t2);
    GEMM_BAR; MM(0, 0, Bl); GEMM_BAR;
    RD_B(1, 1, Bh);
    STAGE(Arow1, 16384, t2);
    GEMM_BAR; MM(0, 1, Bh); GEMM_BAR;
    RD_A(1, 1);
    STAGE(Brow0, 65536 + 32768, t3);
    GEMM_BAR; MM(1, 0, Bl); GEMM_BAR;
    STAGE(Brow1, 65536 + 32768 + 16384, t3);
    GEMM_V4;
    GEMM_BAR; MM(1, 1, Bh); GEMM_BAR;
  }

  float* sum_q2  = sums;
  float* sum_k2  = sums + 16384;
  float* sum_qwk = sums + 32768;
  float* sum_v2  = sums + 49152;

  if (n0 < 8192) {
    // ---- key epilogue: k -> swizzled LDS, then coalesced reduction pass ----
    const int g = n0 >> 11;
#pragma unroll
    for (int mrep = 0; mrep < 8; mrep++) {
      const int rowb = wr * 128 + mrep * 16 + (lane >> 4) * 4;
#pragma unroll
      for (int nrep = 0; nrep < 4; nrep++) {
        const int coll = wc * 64 + nrep * 16 + (lane & 15);
        const float kb = key_b[n0 + coll];
#pragma unroll
        for (int t = 0; t < 4; t++) {
          const int row = rowb + t;
          const int addr = (row * 512 + coll * 2) ^ ((row & 15) << 4);
          *reinterpret_cast<unsigned short*>(lds_c + addr) =
              f2bf(acc[mrep][nrep][t] + kb);
        }
      }
    }
    __syncthreads();
    const int wrow = wid * 32;
    const int lrow = lane >> 3;
    const int lsub = lane & 7;
#pragma unroll
    for (int rr = 0; rr < 4; rr++) {
      const int row = wrow + rr * 8 + lrow;
      const int grow = m0 + row;
      const float* hp = hidden + (size_t)grow * 8192 + n0;
      float a_k2 = 0.f, a_qwk = 0.f, a_q2 = 0.f;
#pragma unroll
      for (int c8 = 0; c8 < 4; c8++) {
        const int lc = c8 * 64 + lsub * 8;
        const int addr = (row * 512 + lc * 2) ^ ((row & 15) << 4);
        bf16x8 k8 = *reinterpret_cast<const bf16x8*>(lds_c + addr);
        f32x4 h0 = *reinterpret_cast<const f32x4*>(hp + lc);
        f32x4 h1 = *reinterpret_cast<const f32x4*>(hp + lc + 4);
        f32x4 qs0 = *reinterpret_cast<const f32x4*>(q_scale + n0 + lc);
        f32x4 qs1 = *reinterpret_cast<const f32x4*>(q_scale + n0 + lc + 4);
        f32x4 ks0 = *reinterpret_cast<const f32x4*>(k_scale + n0 + lc);
        f32x4 ks1 = *reinterpret_cast<const f32x4*>(k_scale + n0 + lc + 4);
#pragma unroll
        for (int i = 0; i < 8; i++) {
          const float kf = (float)k8[i];
          const float hf = (i < 4) ? h0[i] : h1[i - 4];
          const float wf = ((i < 4) ? qs0[i] : qs1[i - 4]) *
                           ((i < 4) ? ks0[i] : ks1[i - 4]);
          a_k2  += kf * kf;
          a_qwk += kf * hf * wf;
          a_q2  += hf * hf;
        }
      }
#pragma unroll
      for (int msk = 1; msk <= 4; msk <<= 1) {
        a_k2  += __shfl_xor(a_k2, msk);
        a_qwk += __shfl_xor(a_qwk, msk);
        a_q2  += __shfl_xor(a_q2, msk);
      }
      if (lsub == 0) {
        const int idx = grow * 4 + g;
        atomicAdd(&sum_k2[idx], a_k2);
        atomicAdd(&sum_qwk[idx], a_qwk);
        atomicAdd(&sum_q2[idx], a_q2);
      }
    }
  } else {
    // ---- value epilogue: store bf16 + sum v^2 per row ----
#pragma unroll
    for (int mrep = 0; mrep < 8; mrep++) {
      const int rowb = m0 + wr * 128 + mrep * 16 + (lane >> 4) * 4;
      float av2[4] = {0.f, 0.f, 0.f, 0.f};
#pragma unroll
      for (int nrep = 0; nrep < 4; nrep++) {
        const int vcol = n0 - 8192 + wc * 64 + nrep * 16 + (lane & 15);
        const float vb = value_b[vcol];
#pragma unroll
        for (int t = 0; t < 4; t++) {
          const float v = acc[mrep][nrep][t] + vb;
          av2[t] += v * v;
          vbuf[(size_t)(rowb + t) * 2048 + vcol] = f2bf(v);
        }
      }
#pragma unroll
      for (int t = 0; t < 4; t++) {
        float a = av2[t];
#pragma unroll
        for (int msk = 1; msk <= 8; msk <<= 1) a += __shfl_xor(a, msk);
        if ((lane & 15) == 0) atomicAdd(&sum_v2[rowb + t], a);
      }
    }
  }
}

// ---------------- conv (r10-proven): in-block gate/rstd; 96x8 grid, 16B access
__global__ __launch_bounds__(256) void k_conv(const unsigned short* __restrict__ vbuf,
                                              const float* __restrict__ sums,
                                              const float* __restrict__ conv_scale,
                                              const float* __restrict__ conv_w,
                                              float* __restrict__ out) {
  const int th = threadIdx.x;
  const int r = blockIdx.x % 3, seg = blockIdx.x / 3;
  const int bg = blockIdx.y;
  const int b = bg >> 2, g = bg & 3;
  const int c8 = th * 8;
  const int ch = g * Cz + c8;
  const int s_begin = seg * 64, s_end = s_begin + 64;

  // gate/rstd for tokens s_begin-9 .. s_begin+63 (73 entries) from sums
  __shared__ float g_lds[73], r_lds[73];
  if (th < 73) {
    const int s = s_begin - 9 + th;
    if (s >= 0) {
      const int t = b * Sz + s;
      const int idx = t * 4 + g;
      const float invC = 1.f / 2048.f;
      const float inv_sqrtC = 0.02209708691f;
      float rqv = rsqrtf(sums[idx] * invC + 1e-6f);                 // sum_q2
      float rkv = rsqrtf(sums[16384 + idx] * invC + 1e-6f);         // sum_k2
      float qk = sums[32768 + idx] * rqv * rkv * inv_sqrtC;         // sum_qwk
      float l = sqrtf(fmaxf(fabsf(qk), 1e-6f));
      l = (qk < 0.f) ? -l : l;
      float gate = 1.f / (1.f + expf(-l));
      g_lds[th] = gate;
      r_lds[th] = rsqrtf(gate * gate * (sums[49152 + t] * invC) + 1e-5f);
    } else {
      g_lds[th] = 0.f; r_lds[th] = 0.f;
    }
  }
  __syncthreads();

  float cs[8], w0[8], w1[8], w2[8], w3[8];
#pragma unroll
  for (int q = 0; q < 2; q++) {
    f32x4 a = *reinterpret_cast<const f32x4*>(conv_scale + ch + q * 4);
    f32x4 t0 = *reinterpret_cast<const f32x4*>(conv_w + 0 * 8192 + ch + q * 4);
    f32x4 t1 = *reinterpret_cast<const f32x4*>(conv_w + 1 * 8192 + ch + q * 4);
    f32x4 t2 = *reinterpret_cast<const f32x4*>(conv_w + 2 * 8192 + ch + q * 4);
    f32x4 t3 = *reinterpret_cast<const f32x4*>(conv_w + 3 * 8192 + ch + q * 4);
#pragma unroll
    for (int i = 0; i < 4; i++) {
      cs[q * 4 + i] = a[i];
      w0[q * 4 + i] = t0[i]; w1[q * 4 + i] = t1[i];
      w2[q * 4 + i] = t2[i]; w3[q * 4 + i] = t3[i];
    }
  }

  const int s0 = s_begin + ((r - s_begin) % 3 + 3) % 3;

  float p1[8], p2[8], p3[8];
  auto ldxn = [&](int s, float* dst) {
    if (s < 0) {
#pragma unroll
      for (int i = 0; i < 8; i++) dst[i] = 0.f;
      return;
    }
    const int t = b * Sz + s;
    const int li = s - s_begin + 9;
    const float grs = g_lds[li] * r_lds[li];
    u16x8 raw = *reinterpret_cast<const u16x8*>(vbuf + (size_t)t * 2048 + c8);
#pragma unroll
    for (int i = 0; i < 8; i++) dst[i] = bf2f(raw[i]) * grs * cs[i];
  };
  ldxn(s0 - 3, p1); ldxn(s0 - 6, p2); ldxn(s0 - 9, p3);

  for (int s = s0; s < s_end; s += 3) {
    const int t = b * Sz + s;
    const int li = s - s_begin + 9;
    const float gate = g_lds[li];
    const float rsc = r_lds[li];
    u16x8 raw = *reinterpret_cast<const u16x8*>(vbuf + (size_t)t * 2048 + c8);
    f32x4 o0, o1;
#pragma unroll
    for (int i = 0; i < 8; i++) {
      float v = bf2f(raw[i]) * gate;
      float xn = v * rsc * cs[i];
      float y = w3[i] * xn + w2[i] * p1[i] + w1[i] * p2[i] + w0[i] * p3[i];
      float sy = y / (1.f + expf(-y));
      float ov = v + sy;
      if (i < 4) o0[i] = ov; else o1[i - 4] = ov;
      p3[i] = p2[i]; p2[i] = p1[i]; p1[i] = xn;
    }
    float* op = out + (size_t)t * (Gz * Cz) + ch;
    *reinterpret_cast<f32x4*>(op) = o0;
    *reinterpret_cast<f32x4*>(op + 4) = o1;
  }
}

extern "C" void kernel_launch(void* const* d_in, const int* in_sizes, int n_in,
                              void* d_out, int out_size, void* d_ws, size_t ws_size,
                              hipStream_t stream) {
  const float* hidden     = (const float*)d_in[0];
  const int*   hashids    = (const int*)d_in[1];
  const float* table      = (const float*)d_in[2];
  const float* key_w      = (const float*)d_in[3];
  const float* key_b      = (const float*)d_in[4];
  const float* k_scale    = (const float*)d_in[5];
  const float* q_scale    = (const float*)d_in[6];
  const float* value_w    = (const float*)d_in[7];
  const float* value_b    = (const float*)d_in[8];
  const float* conv_scale = (const float*)d_in[9];
  const float* conv_w     = (const float*)d_in[10];
  float* out = (float*)d_out;
  char* ws = (char*)d_ws;

  unsigned short* emb  = (unsigned short*)(ws + 0);          //  8,388,608 B
  unsigned short* Wt   = (unsigned short*)(ws + 8388608);    // 20,971,520 B
  unsigned short* vbuf = (unsigned short*)(ws + 29360128);   // 16,777,216 B
  float* sums  = (float*)(ws + 46137344);                    //    212,992 B

  k_prep<<<dim3(14544), dim3(256), 0, stream>>>(key_w, value_w, table, hashids,
                                                Wt, emb, sums);
  k_gemm8f<<<dim3(640), dim3(512), 0, stream>>>(emb, Wt, hidden, key_b, value_b,
                                                q_scale, k_scale, sums, vbuf);
  k_conv<<<dim3(96, 8), dim3(256), 0, stream>>>(vbuf, sums, conv_scale, conv_w, out);
}